// Round 3
// baseline (597.440 us; speedup 1.0000x reference)
//
#include <hip/hip_runtime.h>
#include <math.h>

#define BB 8
#define CIN 12
#define LL 4096
#define DD 64
#define DIx 128
#define DSx 16
#define RR 10
#define KK 15
#define NCH 32      // scan chunks
#define CLEN 128    // LL/NCH
#define OUTL 40960  // LL*RR

// ---------------------------------------------------------------
// Direct conv1d, K=15, pad 7. Each thread: 4 consecutive l, COT co's.
// Weights wave-uniform -> scalar loads. Input window in 20 regs/ci.
// ---------------------------------------------------------------
template<int CI, int CO, int COT, bool LEAKY>
__global__ __launch_bounds__(256) void k_conv(const float* __restrict__ in,
        const float* __restrict__ w, const float* __restrict__ bias,
        float* __restrict__ out) {
    const int LT = 1024;
    int tid = threadIdx.x;
    int bid = blockIdx.x;
    const int nlt = LL / LT;        // 4
    const int ncog = CO / COT;
    int lt = bid % nlt;
    int cog = (bid / nlt) % ncog;
    int b = bid / (nlt * ncog);
    int l0 = lt * LT + tid * 4;
    int co0 = cog * COT;

    float acc[COT][4];
#pragma unroll
    for (int c = 0; c < COT; ++c) {
        float bv = bias[co0 + c];
#pragma unroll
        for (int j = 0; j < 4; ++j) acc[c][j] = bv;
    }

    for (int ci = 0; ci < CI; ++ci) {
        const float* inp = in + ((size_t)b * CI + ci) * LL;
        float in20[20];
#pragma unroll
        for (int q = 0; q < 5; ++q) {
            int gi = l0 - 8 + q * 4;
            if (gi >= 0 && gi + 3 < LL) {
                float4 v = *(const float4*)(inp + gi);
                in20[q*4+0] = v.x; in20[q*4+1] = v.y;
                in20[q*4+2] = v.z; in20[q*4+3] = v.w;
            } else {
#pragma unroll
                for (int j = 0; j < 4; ++j) {
                    int g = gi + j;
                    in20[q*4+j] = (g >= 0 && g < LL) ? inp[g] : 0.f;
                }
            }
        }
#pragma unroll
        for (int c = 0; c < COT; ++c) {
            const float* wp = w + ((size_t)(co0 + c) * CI + ci) * KK;
#pragma unroll
            for (int k = 0; k < KK; ++k) {
                float wv = wp[k];
#pragma unroll
                for (int j = 0; j < 4; ++j)
                    acc[c][j] += wv * in20[j + k + 1];   // offset (l0+j-7+k)-(l0-8)
            }
        }
    }
#pragma unroll
    for (int c = 0; c < COT; ++c) {
        float r[4];
#pragma unroll
        for (int j = 0; j < 4; ++j) {
            float v = acc[c][j];
            if (LEAKY) v = (v >= 0.f) ? v : 0.01f * v;
            r[j] = v;
        }
        float4 v4 = make_float4(r[0], r[1], r[2], r[3]);
        *(float4*)(out + ((size_t)b * CO + co0 + c) * LL + l0) = v4;
    }
}

// ---------------------------------------------------------------
// Transpose per-batch: in (B, X, Y) -> out (B, Y, X). 64x64 LDS tiles.
// ---------------------------------------------------------------
__global__ __launch_bounds__(256) void k_transpose(const float* __restrict__ in,
        float* __restrict__ out, int X, int Y) {
    __shared__ float tile[64][65];
    int tid = threadIdx.x;
    int bid = blockIdx.x;
    int nty = Y >> 6;
    int ntx = X >> 6;
    int tyb = bid % nty;
    int txb = (bid / nty) % ntx;
    int b = bid / (nty * ntx);
    int x0 = txb << 6, y0 = tyb << 6;
    const float* ip = in + (size_t)b * X * Y;
    float* op = out + (size_t)b * X * Y;
#pragma unroll
    for (int r = 0; r < 16; ++r) {
        int idx = r * 256 + tid;
        int i = idx >> 6, j = idx & 63;
        tile[i][j] = ip[(size_t)(x0 + i) * Y + (y0 + j)];
    }
    __syncthreads();
#pragma unroll
    for (int r = 0; r < 16; ++r) {
        int idx = r * 256 + tid;
        int j = idx >> 6, i = idx & 63;
        op[(size_t)(y0 + j) * X + (x0 + i)] = tile[i][j];
    }
}

// ---------------------------------------------------------------
// in_proj GEMM: C(32768,256) = A(32768,64) * W(256,64)^T
// Block tile 128x128, micro 8x8 (split 4+4), threads 16x16.
// ---------------------------------------------------------------
__global__ __launch_bounds__(256) void k_gemm_inproj(const float* __restrict__ A,
        const float* __restrict__ W, float* __restrict__ C) {
    __shared__ float At[64 * 132];
    __shared__ float Wt[64 * 132];
    int tid = threadIdx.x;
    int bid = blockIdx.x;
    int nb = bid & 1;
    int mb = bid >> 1;
    int row0 = mb * 128;
    int n0 = nb * 128;
#pragma unroll
    for (int it = 0; it < 8; ++it) {
        int lin = it * 1024 + tid * 4;
        int m = lin >> 6, k = lin & 63;
        float4 v = *(const float4*)(A + (size_t)(row0 + m) * 64 + k);
        At[(k+0)*132 + m] = v.x; At[(k+1)*132 + m] = v.y;
        At[(k+2)*132 + m] = v.z; At[(k+3)*132 + m] = v.w;
    }
#pragma unroll
    for (int it = 0; it < 8; ++it) {
        int lin = it * 1024 + tid * 4;
        int n = lin >> 6, k = lin & 63;
        float4 v = *(const float4*)(W + (size_t)(n0 + n) * 64 + k);
        Wt[(k+0)*132 + n] = v.x; Wt[(k+1)*132 + n] = v.y;
        Wt[(k+2)*132 + n] = v.z; Wt[(k+3)*132 + n] = v.w;
    }
    __syncthreads();
    int tx = tid & 15, ty = tid >> 4;
    float acc[2][2][4][4] = {};
#pragma unroll 4
    for (int k = 0; k < 64; ++k) {
        float4 aLo = *(float4*)&At[k*132 + ty*4];
        float4 aHi = *(float4*)&At[k*132 + 64 + ty*4];
        float4 bLo = *(float4*)&Wt[k*132 + tx*4];
        float4 bHi = *(float4*)&Wt[k*132 + 64 + tx*4];
        float a0[4] = {aLo.x, aLo.y, aLo.z, aLo.w};
        float a1[4] = {aHi.x, aHi.y, aHi.z, aHi.w};
        float b0[4] = {bLo.x, bLo.y, bLo.z, bLo.w};
        float b1[4] = {bHi.x, bHi.y, bHi.z, bHi.w};
#pragma unroll
        for (int mm = 0; mm < 4; ++mm)
#pragma unroll
            for (int nn = 0; nn < 4; ++nn) {
                acc[0][0][mm][nn] += a0[mm] * b0[nn];
                acc[0][1][mm][nn] += a0[mm] * b1[nn];
                acc[1][0][mm][nn] += a1[mm] * b0[nn];
                acc[1][1][mm][nn] += a1[mm] * b1[nn];
            }
    }
#pragma unroll
    for (int qm = 0; qm < 2; ++qm)
#pragma unroll
        for (int mm = 0; mm < 4; ++mm) {
            int row = row0 + qm*64 + ty*4 + mm;
#pragma unroll
            for (int qn = 0; qn < 2; ++qn) {
                float4 v = make_float4(acc[qm][qn][mm][0], acc[qm][qn][mm][1],
                                       acc[qm][qn][mm][2], acc[qm][qn][mm][3]);
                *(float4*)(C + (size_t)row * 256 + n0 + qn*64 + tx*4) = v;
            }
        }
}

// ---------------------------------------------------------------
// Generic N=64 GEMM: out(32768,64) = A(32768,128) * W(NW,128)^T
// GUARD: zero-pad W rows >= NW.  MODE 1: add residual res(row,64).
// ---------------------------------------------------------------
template<int NW, bool GUARD, int MODE>
__global__ __launch_bounds__(256) void k_gemm64(const float* __restrict__ A,
        const float* __restrict__ W, const float* __restrict__ res,
        float* __restrict__ out) {
    __shared__ float At[64 * 132];
    __shared__ float Wt[64 * 68];
    int tid = threadIdx.x;
    int row0 = blockIdx.x * 128;
    int tx = tid & 15, ty = tid >> 4;
    float acc[2][4][4] = {};
#pragma unroll
    for (int kt = 0; kt < 2; ++kt) {
        __syncthreads();
#pragma unroll
        for (int it = 0; it < 8; ++it) {
            int lin = it * 1024 + tid * 4;
            int m = lin >> 6, k = lin & 63;
            float4 v = *(const float4*)(A + (size_t)(row0 + m) * 128 + kt*64 + k);
            At[(k+0)*132 + m] = v.x; At[(k+1)*132 + m] = v.y;
            At[(k+2)*132 + m] = v.z; At[(k+3)*132 + m] = v.w;
        }
#pragma unroll
        for (int it = 0; it < 4; ++it) {
            int lin = it * 1024 + tid * 4;
            int n = lin >> 6, k = lin & 63;
            float4 v = make_float4(0.f, 0.f, 0.f, 0.f);
            if (!GUARD || n < NW)
                v = *(const float4*)(W + (size_t)n * 128 + kt*64 + k);
            Wt[(k+0)*68 + n] = v.x; Wt[(k+1)*68 + n] = v.y;
            Wt[(k+2)*68 + n] = v.z; Wt[(k+3)*68 + n] = v.w;
        }
        __syncthreads();
#pragma unroll 4
        for (int k = 0; k < 64; ++k) {
            float4 aLo = *(float4*)&At[k*132 + ty*4];
            float4 aHi = *(float4*)&At[k*132 + 64 + ty*4];
            float4 b4  = *(float4*)&Wt[k*68 + tx*4];
            float a0[4] = {aLo.x, aLo.y, aLo.z, aLo.w};
            float a1[4] = {aHi.x, aHi.y, aHi.z, aHi.w};
            float bv[4] = {b4.x, b4.y, b4.z, b4.w};
#pragma unroll
            for (int mm = 0; mm < 4; ++mm)
#pragma unroll
                for (int nn = 0; nn < 4; ++nn) {
                    acc[0][mm][nn] += a0[mm] * bv[nn];
                    acc[1][mm][nn] += a1[mm] * bv[nn];
                }
        }
    }
#pragma unroll
    for (int qm = 0; qm < 2; ++qm)
#pragma unroll
        for (int mm = 0; mm < 4; ++mm) {
            int row = row0 + qm*64 + ty*4 + mm;
            float4 v = make_float4(acc[qm][mm][0], acc[qm][mm][1],
                                   acc[qm][mm][2], acc[qm][mm][3]);
            if (MODE == 1) {
                float4 r = *(const float4*)(res + (size_t)row * 64 + tx*4);
                v.x += r.x; v.y += r.y; v.z += r.z; v.w += r.w;
            }
            *(float4*)(out + (size_t)row * 64 + tx*4) = v;
        }
}

// ---------------------------------------------------------------
// Depthwise causal conv (DC=4) + silu. xz (B,L,256) cols 0..127 are xs.
// ---------------------------------------------------------------
__global__ __launch_bounds__(256) void k_dwconv(const float* __restrict__ xz,
        const float* __restrict__ w, const float* __restrict__ bias,
        float* __restrict__ xs_act) {
    int idx = blockIdx.x * 256 + threadIdx.x;   // B*L*128
    int d = idx & 127;
    int row = idx >> 7;                          // b*L + l
    int l = row & (LL - 1);
    float s = bias[d];
    const float* wp = w + d * 4;
#pragma unroll
    for (int j = 0; j < 4; ++j) {
        int li = l - 3 + j;
        if (li >= 0) s += xz[(size_t)(row - 3 + j) * 256 + d] * wp[j];
    }
    float sg = 1.f / (1.f + __expf(-s));
    xs_act[idx] = s * sg;
}

// ---------------------------------------------------------------
// dt = softplus(dbl[:, :4] @ dt_proj_w^T + b)
// ---------------------------------------------------------------
__global__ __launch_bounds__(256) void k_dtproj(const float* __restrict__ dbl,
        const float* __restrict__ w, const float* __restrict__ bias,
        float* __restrict__ dt) {
    int idx = blockIdx.x * 256 + threadIdx.x;   // B*L*128
    int d = idx & 127;
    int row = idx >> 7;
    float4 di = *(const float4*)(dbl + (size_t)row * 64);
    float4 w4 = *(const float4*)(w + d * 4);
    float v = di.x*w4.x + di.y*w4.y + di.z*w4.z + di.w*w4.w + bias[d];
    dt[idx] = (v > 15.f) ? v : log1pf(__expf(v));
}

// ---------------------------------------------------------------
// Scan phase 1: per (b,d,s,chunk) compute P=prod(dA), Q=h(end|h0=0)
// wave = 4 d-channels x 16 states. P/Q layout [chunk][chain].
// ---------------------------------------------------------------
__global__ __launch_bounds__(64) void k_scan1(const float* __restrict__ dt,
        const float* __restrict__ xs, const float* __restrict__ dbl,
        const float* __restrict__ A_log, float* __restrict__ P,
        float* __restrict__ Q) {
    int lane = threadIdx.x;
    int s = lane & 15, dloc = lane >> 4;
    int bid = blockIdx.x;
    int c = bid & (NCH - 1);
    int dg = (bid >> 5) & 31;
    int b = bid >> 10;
    int d = dg * 4 + dloc;
    float Ads = -__expf(A_log[d * DSx + s]);
    float h = 0.f, p = 1.f;
    int t0 = c * CLEN;
    for (int t = t0; t < t0 + CLEN; ++t) {
        size_t row = (size_t)b * LL + t;
        float dtv = dt[row * 128 + d];
        float xv  = xs[row * 128 + d];
        float Bv  = dbl[row * 64 + 4 + s];
        float da  = __expf(dtv * Ads);
        h = da * h + dtv * Bv * xv;
        p *= da;
    }
    int chain = (b * DIx + d) * DSx + s;
    P[(size_t)c * 16384 + chain] = p;
    Q[(size_t)c * 16384 + chain] = h;
}

// ---------------------------------------------------------------
// Scan phase 2: sequential prefix over chunks per chain.
// ---------------------------------------------------------------
__global__ __launch_bounds__(256) void k_scan2(const float* __restrict__ P,
        const float* __restrict__ Q, float* __restrict__ Hin) {
    int chain = blockIdx.x * 256 + threadIdx.x;  // 16384
    float carry = 0.f;
    for (int c = 0; c < NCH; ++c) {
        Hin[(size_t)c * 16384 + chain] = carry;
        carry = P[(size_t)c * 16384 + chain] * carry + Q[(size_t)c * 16384 + chain];
    }
}

// ---------------------------------------------------------------
// Scan phase 3: recompute with correct h_in, emit y (fused +xs*D, *silu(z))
// ---------------------------------------------------------------
__global__ __launch_bounds__(64) void k_scan3(const float* __restrict__ dt,
        const float* __restrict__ xs, const float* __restrict__ dbl,
        const float* __restrict__ A_log, const float* __restrict__ Hin,
        const float* __restrict__ xz, const float* __restrict__ Dssm,
        float* __restrict__ ym) {
    int lane = threadIdx.x;
    int s = lane & 15, dloc = lane >> 4;
    int bid = blockIdx.x;
    int c = bid & (NCH - 1);
    int dg = (bid >> 5) & 31;
    int b = bid >> 10;
    int d = dg * 4 + dloc;
    float Ads = -__expf(A_log[d * DSx + s]);
    int chain = (b * DIx + d) * DSx + s;
    float h = Hin[(size_t)c * 16384 + chain];
    float Dv = Dssm[d];
    int t0 = c * CLEN;
    for (int t = t0; t < t0 + CLEN; ++t) {
        size_t row = (size_t)b * LL + t;
        float dtv = dt[row * 128 + d];
        float xv  = xs[row * 128 + d];
        float Bv  = dbl[row * 64 + 4 + s];
        float Cv  = dbl[row * 64 + 20 + s];
        float da  = __expf(dtv * Ads);
        h = da * h + dtv * Bv * xv;
        float part = h * Cv;
        part += __shfl_xor(part, 1);
        part += __shfl_xor(part, 2);
        part += __shfl_xor(part, 4);
        part += __shfl_xor(part, 8);
        if (s == 0) {
            float y = part + xv * Dv;
            float zv = xz[row * 256 + 128 + d];
            y *= zv / (1.f + __expf(-zv));
            ym[row * 128 + d] = y;
        }
    }
}

// ---------------------------------------------------------------
// BatchNorm stats: one block per channel -> mean, rstd
// ---------------------------------------------------------------
__global__ __launch_bounds__(256) void k_bnstats(const float* __restrict__ xm,
        float* __restrict__ stats) {
    int c = blockIdx.x;
    int tid = threadIdx.x;
    float s = 0.f, ss = 0.f;
    for (int b = 0; b < BB; ++b) {
        const float* p = xm + ((size_t)b * DD + c) * LL;
        for (int l = tid; l < LL; l += 256) {
            float v = p[l];
            s += v; ss += v * v;
        }
    }
    for (int o = 32; o > 0; o >>= 1) {
        s  += __shfl_down(s, o);
        ss += __shfl_down(ss, o);
    }
    __shared__ float red[8];
    int wid = tid >> 6;
    if ((tid & 63) == 0) { red[wid] = s; red[4 + wid] = ss; }
    __syncthreads();
    if (tid == 0) {
        float S  = red[0] + red[1] + red[2] + red[3];
        float SS = red[4] + red[5] + red[6] + red[7];
        const float inv = 1.f / (float)(BB * LL);
        float mean = S * inv;
        float var  = SS * inv - mean * mean;
        stats[c] = mean;
        stats[64 + c] = rsqrtf(var + 1e-5f);
    }
}

// ---------------------------------------------------------------
// BN apply + residual: xfinal = (xmerge-mean)*rstd*g + b + x_in
// ---------------------------------------------------------------
__global__ __launch_bounds__(256) void k_bnapply(const float* __restrict__ xm,
        const float* __restrict__ stats, const float* __restrict__ gamma,
        const float* __restrict__ beta, const float* __restrict__ xin,
        float* __restrict__ out) {
    int i = blockIdx.x * 256 + threadIdx.x;     // B*64*L/4
    size_t f = (size_t)i * 4;
    int c = (int)((f / LL) & 63);
    float4 v = *(const float4*)(xm + f);
    float4 r = *(const float4*)(xin + f);
    float g = gamma[c] * stats[64 + c];
    float sh = beta[c] - stats[c] * g;
    v.x = v.x * g + sh + r.x;
    v.y = v.y * g + sh + r.y;
    v.z = v.z * g + sh + r.z;
    v.w = v.w * g + sh + r.w;
    *(float4*)(out + f) = v;
}

// ---------------------------------------------------------------
// PixelShuffle(r=10) + linear upsample of x + add -> d_out
// ---------------------------------------------------------------
__global__ __launch_bounds__(256) void k_final(const float* __restrict__ xp,
        const float* __restrict__ x, float* __restrict__ out) {
    int i = blockIdx.x * 256 + threadIdx.x;     // B*12*OUTL
    int j = i % OUTL;
    int c = (i / OUTL) % 12;
    int b = i / (OUTL * 12);
    int r = j % RR, l = j / RR;
    float ps = xp[((size_t)b * 120 + r * 12 + c) * LL + l];
    float src = ((float)j + 0.5f) * 0.1f - 0.5f;
    src = fmaxf(src, 0.f);
    int i0 = (int)src;
    if (i0 > LL - 1) i0 = LL - 1;
    int i1 = (i0 + 1 < LL) ? i0 + 1 : LL - 1;
    float frac = src - (float)i0;
    const float* xr = x + ((size_t)b * 12 + c) * LL;
    float up = xr[i0] * (1.f - frac) + xr[i1] * frac;
    out[i] = ps + up;
}

// ---------------------------------------------------------------
extern "C" void kernel_launch(void* const* d_in, const int* in_sizes, int n_in,
                              void* d_out, int out_size, void* d_ws, size_t ws_size,
                              hipStream_t stream) {
    const float* x          = (const float*)d_in[0];
    const float* conv_in_w  = (const float*)d_in[1];
    const float* conv_in_b  = (const float*)d_in[2];
    const float* in_proj_w  = (const float*)d_in[3];
    const float* dw_w       = (const float*)d_in[4];
    const float* dw_b       = (const float*)d_in[5];
    const float* x_proj_w   = (const float*)d_in[6];
    const float* dt_w       = (const float*)d_in[7];
    const float* dt_b       = (const float*)d_in[8];
    const float* A_log      = (const float*)d_in[9];
    const float* Dssm       = (const float*)d_in[10];
    const float* out_proj_w = (const float*)d_in[11];
    const float* cm_w       = (const float*)d_in[12];
    const float* cm_b       = (const float*)d_in[13];
    const float* bn_g       = (const float*)d_in[14];
    const float* bn_be      = (const float*)d_in[15];
    const float* ps_w       = (const float*)d_in[16];
    const float* ps_b       = (const float*)d_in[17];

    float* ws = (float*)d_ws;
    float* xin_bdl = ws;                    // 2,097,152
    float* xin_bld = ws + 2097152;          // 2,097,152
    float* xz      = ws + 4194304;          // 8,388,608
    float* xs_act  = ws + 12582912;         // 4,194,304
    float* dbl64   = ws + 16777216;         // 2,097,152
    float* dtb     = ws + 18874368;         // 4,194,304
    float* P       = ws + 23068672;         // 524,288
    float* Q       = ws + 23592960;         // 524,288
    float* Hin     = ws + 24117248;         // 524,288
    float* ym      = ws + 24641536;         // 4,194,304
    float* xm_bdl  = ws + 28835840;         // 2,097,152
    float* stats   = ws + 30932992;         // 128
    // aliases (sources dead after scan phase 3)
    float* xm_bld  = dbl64;
    float* xmerge  = dtb;
    float* xfinal  = xs_act;
    float* xp      = xz;

    k_conv<CIN, 64, 4, true><<<512, 256, 0, stream>>>(x, conv_in_w, conv_in_b, xin_bdl);
    k_transpose<<<512, 256, 0, stream>>>(xin_bdl, xin_bld, 64, LL);
    k_gemm_inproj<<<512, 256, 0, stream>>>(xin_bld, in_proj_w, xz);
    k_dwconv<<<16384, 256, 0, stream>>>(xz, dw_w, dw_b, xs_act);
    k_gemm64<36, true, 0><<<256, 256, 0, stream>>>(xs_act, x_proj_w, nullptr, dbl64);
    k_dtproj<<<16384, 256, 0, stream>>>(dbl64, dt_w, dt_b, dtb);
    k_scan1<<<8192, 64, 0, stream>>>(dtb, xs_act, dbl64, A_log, P, Q);
    k_scan2<<<64, 256, 0, stream>>>(P, Q, Hin);
    k_scan3<<<8192, 64, 0, stream>>>(dtb, xs_act, dbl64, A_log, Hin, xz, Dssm, ym);
    k_gemm64<64, false, 1><<<256, 256, 0, stream>>>(ym, out_proj_w, xin_bld, xm_bld);
    k_transpose<<<512, 256, 0, stream>>>(xm_bld, xm_bdl, LL, 64);
    k_conv<64, 64, 4, false><<<512, 256, 0, stream>>>(xm_bdl, cm_w, cm_b, xmerge);
    k_bnstats<<<64, 256, 0, stream>>>(xmerge, stats);
    k_bnapply<<<2048, 256, 0, stream>>>(xmerge, stats, bn_g, bn_be, xin_bdl, xfinal);
    k_conv<64, 120, 4, false><<<960, 256, 0, stream>>>(xfinal, ps_w, ps_b, xp);
    k_final<<<15360, 256, 0, stream>>>(xp, x, (float*)d_out);
}